// Round 1
// baseline (143.071 us; speedup 1.0000x reference)
//
#include <hip/hip_runtime.h>
#include <cstdint>

#define DD   256   // embedding dim
#define NS   320   // n_support
#define NQ   2048  // n_query
#define NWAY 20
#define QT   8     // queries per block (kernel B / C)
#define SB   4     // supports per block (kernel A)

// A: spbT[d*NS + s] = sum_k support[s,k] * W1[(DD+k)*DD + d] + b1[d]
// thread = d (coalesced W1 col reads), support reads are block-uniform -> scalar.
__global__ __launch_bounds__(256) void proj_support_kernel(
    const float* __restrict__ sup, const float* __restrict__ W1,
    const float* __restrict__ b1, float* __restrict__ spbT) {
  const int d  = threadIdx.x;
  const int s0 = blockIdx.x * SB;
  float acc[SB];
#pragma unroll
  for (int i = 0; i < SB; ++i) acc[i] = 0.f;
  const float* wcol = W1 + (size_t)DD * DD + d;
#pragma unroll 4
  for (int k = 0; k < DD; ++k) {
    const float wv = wcol[(size_t)k * DD];
#pragma unroll
    for (int i = 0; i < SB; ++i)
      acc[i] += sup[(s0 + i) * DD + k] * wv;
  }
  const float bb = b1[d];
#pragma unroll
  for (int i = 0; i < SB; ++i)
    spbT[d * NS + s0 + i] = acc[i] + bb;   // scattered store, tiny total (320 KB)
}

// B: qp[q*DD + d] = sum_k query[q,k] * W1[k*DD + d]
__global__ __launch_bounds__(256) void proj_query_kernel(
    const float* __restrict__ qe, const float* __restrict__ W1,
    float* __restrict__ qp) {
  const int d  = threadIdx.x;
  const int q0 = blockIdx.x * QT;
  float acc[QT];
#pragma unroll
  for (int i = 0; i < QT; ++i) acc[i] = 0.f;
#pragma unroll 4
  for (int k = 0; k < DD; ++k) {
    const float wv = W1[(size_t)k * DD + d];   // coalesced
#pragma unroll
    for (int i = 0; i < QT; ++i)
      acc[i] += qe[(q0 + i) * DD + k] * wv;    // uniform -> s_load
  }
#pragma unroll
  for (int i = 0; i < QT; ++i)
    qp[(size_t)(q0 + i) * DD + d] = acc[i];    // coalesced
}

// C: scores -> softmax -> class-weighted sums, one 8-query tile per block,
// thread = support index. spbT loads coalesced; qp/W2 loads uniform.
__global__ __launch_bounds__(NS) void matchnet_kernel(
    const float* __restrict__ qp, const float* __restrict__ spbT,
    const float* __restrict__ W2, const int* __restrict__ labels,
    float* __restrict__ out) {
  __shared__ float lds_cs[QT * NWAY];
  __shared__ float lds_wm[8];
  const int tid = threadIdx.x;
  const int q0  = blockIdx.x * QT;

  if (tid < QT * NWAY) lds_cs[tid] = 0.f;      // re-poisoned ws/out: init here
  const int mylab = labels[tid];               // tid < 320 always

  float acc[QT];
#pragma unroll
  for (int i = 0; i < QT; ++i) acc[i] = 0.f;
  const float* qr0 = qp + (size_t)q0 * DD;

#pragma unroll 2
  for (int d = 0; d < DD; d += 4) {
    const float sv0 = spbT[(d + 0) * NS + tid];
    const float sv1 = spbT[(d + 1) * NS + tid];
    const float sv2 = spbT[(d + 2) * NS + tid];
    const float sv3 = spbT[(d + 3) * NS + tid];
    const float w0 = W2[d + 0];
    const float w1 = W2[d + 1];
    const float w2 = W2[d + 2];
    const float w3 = W2[d + 3];
#pragma unroll
    for (int i = 0; i < QT; ++i) {
      const float* qr = qr0 + i * DD + d;      // uniform address -> scalar loads
      acc[i] += fmaxf(qr[0] + sv0, 0.f) * w0
              + fmaxf(qr[1] + sv1, 0.f) * w1
              + fmaxf(qr[2] + sv2, 0.f) * w2
              + fmaxf(qr[3] + sv3, 0.f) * w3;
    }
  }

  // One shared stability constant M (exact softmax is invariant to it).
  float m = acc[0];
#pragma unroll
  for (int i = 1; i < QT; ++i) m = fmaxf(m, acc[i]);
#pragma unroll
  for (int off = 32; off > 0; off >>= 1)
    m = fmaxf(m, __shfl_xor(m, off));
  if ((tid & 63) == 0) lds_wm[tid >> 6] = m;
  __syncthreads();
  float M = lds_wm[0];
#pragma unroll
  for (int w = 1; w < 5; ++w) M = fmaxf(M, lds_wm[w]);

  // exp in registers; aggregate straight into per-class buckets (own label).
#pragma unroll
  for (int i = 0; i < QT; ++i) {
    const float w = __expf(acc[i] - M);
    atomicAdd(&lds_cs[i * NWAY + mylab], w);
  }
  __syncthreads();

  if (tid < QT * NWAY) {
    const int i = tid / NWAY;
    const int c = tid - i * NWAY;
    float tot = 0.f;
#pragma unroll
    for (int j = 0; j < NWAY; ++j) tot += lds_cs[i * NWAY + j];
    out[(size_t)(q0 + i) * NWAY + c] = lds_cs[i * NWAY + c] / tot;
  }
}

extern "C" void kernel_launch(void* const* d_in, const int* in_sizes, int n_in,
                              void* d_out, int out_size, void* d_ws, size_t ws_size,
                              hipStream_t stream) {
  const float* sup = (const float*)d_in[0];   // [320,256]
  const float* qe  = (const float*)d_in[1];   // [2048,256]
  const int*   lab = (const int*)d_in[2];     // [320] int32
  const float* W1  = (const float*)d_in[3];   // [512,256]
  const float* b1  = (const float*)d_in[4];   // [256]
  const float* W2  = (const float*)d_in[5];   // [256]
  // b2 (d_in[6]) is softmax-invariant -> unused. n_way/n_shot hardcoded.
  float* out  = (float*)d_out;                // [2048,20]
  float* spbT = (float*)d_ws;                 // 256*320 floats
  float* qpr  = spbT + (size_t)DD * NS;       // 2048*256 floats

  proj_support_kernel<<<NS / SB, 256, 0, stream>>>(sup, W1, b1, spbT);
  proj_query_kernel<<<NQ / QT, 256, 0, stream>>>(qe, W1, qpr);
  matchnet_kernel<<<NQ / QT, NS, 0, stream>>>(qpr, spbT, W2, lab, out);
}

// Round 2
// 103.248 us; speedup vs baseline: 1.3857x; 1.3857x over previous
//
#include <hip/hip_runtime.h>
#include <cstdint>

#define DD   256   // embedding dim
#define NS   320   // n_support
#define NQ   2048  // n_query
#define NWAY 20
#define QT   4     // queries per block (both kernels)
#define SBLK 4     // supports per proj block
#define NQB  (NQ / QT)   // 512 query-proj blocks
#define NSB  (NS / SBLK) // 80 support-proj blocks
#define MT   640   // matchnet block size (10 waves: 5 low-d, 5 high-d)

// Fused projections: blocks [0,512) do q_proj (QT=4 queries each),
// blocks [512,592) do s_proj (+b1) stored d-major for coalesced matchnet reads.
// thread = d. W1 column loads coalesced; qe/sup row loads block-uniform -> scalar.
__global__ __launch_bounds__(256) void proj_kernel(
    const float* __restrict__ sup, const float* __restrict__ qe,
    const float* __restrict__ W1, const float* __restrict__ b1,
    float* __restrict__ qp, float* __restrict__ spbT) {
  const int d = threadIdx.x;
  const int b = blockIdx.x;
  if (b < NQB) {
    const int q0 = b * QT;
    float acc[QT] = {0.f, 0.f, 0.f, 0.f};
    const float* w = W1 + d;
#pragma unroll 8
    for (int k = 0; k < DD; ++k) {
      const float wv = w[(size_t)k * DD];
#pragma unroll
      for (int i = 0; i < QT; ++i)
        acc[i] += qe[(q0 + i) * DD + k] * wv;   // uniform -> s_load
    }
#pragma unroll
    for (int i = 0; i < QT; ++i)
      qp[(size_t)(q0 + i) * DD + d] = acc[i];   // coalesced
  } else {
    const int s0 = (b - NQB) * SBLK;
    float acc[SBLK] = {0.f, 0.f, 0.f, 0.f};
    const float* w = W1 + (size_t)DD * DD + d;
#pragma unroll 8
    for (int k = 0; k < DD; ++k) {
      const float wv = w[(size_t)k * DD];
#pragma unroll
      for (int i = 0; i < SBLK; ++i)
        acc[i] += sup[(s0 + i) * DD + k] * wv;
    }
    const float bb = b1[d];
#pragma unroll
    for (int i = 0; i < SBLK; ++i)
      spbT[d * NS + s0 + i] = acc[i] + bb;      // scattered store, tiny (320 KB)
  }
}

// matchnet: block = 640 threads = 10 waves. Waves 0-4: support s=t, d in [0,128);
// waves 5-9: same supports, d in [128,256). q-tile + W2 staged in LDS (uniform
// broadcast reads). Partial scores combined via LDS, then softmax + per-class
// label buckets (LDS atomics), logits = classsum/total (b2 softmax-invariant).
__global__ __launch_bounds__(MT) void matchnet_kernel(
    const float* __restrict__ qp, const float* __restrict__ spbT,
    const float* __restrict__ W2, const int* __restrict__ labels,
    float* __restrict__ out) {
  __shared__ float qlds[QT * DD];       // 4 KB
  __shared__ float wlds[DD];            // 1 KB
  __shared__ float part[QT][NS];        // 5 KB
  __shared__ float lds_cs[QT * NWAY];   // 320 B
  __shared__ float lds_wm[5];
  const int t  = threadIdx.x;
  const int q0 = blockIdx.x * QT;

  // Stage q-tile (256 float4) + W2 (64 float4) into LDS; zero class buckets.
  if (t < QT * DD / 4) {
    ((float4*)qlds)[t] = ((const float4*)(qp + (size_t)q0 * DD))[t];
  } else if (t < QT * DD / 4 + DD / 4) {
    const int j = t - QT * DD / 4;
    ((float4*)wlds)[j] = ((const float4*)W2)[j];
  }
  if (t < QT * NWAY) lds_cs[t] = 0.f;   // ws/out re-poisoned: must init
  __syncthreads();

  const int half = t / NS;              // wave-uniform (NS = 5 full waves)
  const int s    = t - half * NS;
  const int d0   = half * (DD / 2);
  const int lab  = labels[s];

  float acc[QT] = {0.f, 0.f, 0.f, 0.f};
  const float* pS = spbT + d0 * NS + s;
#pragma unroll 2
  for (int dd = 0; dd < DD / 2; dd += 4) {
    const int d = d0 + dd;
    const float sv0 = pS[(dd + 0) * NS];   // coalesced, L2-resident
    const float sv1 = pS[(dd + 1) * NS];
    const float sv2 = pS[(dd + 2) * NS];
    const float sv3 = pS[(dd + 3) * NS];
    const float4 wv = *(const float4*)(wlds + d);   // uniform -> broadcast
#pragma unroll
    for (int i = 0; i < QT; ++i) {
      const float4 qv = *(const float4*)(qlds + i * DD + d);  // broadcast
      acc[i] += fmaxf(qv.x + sv0, 0.f) * wv.x
              + fmaxf(qv.y + sv1, 0.f) * wv.y
              + fmaxf(qv.z + sv2, 0.f) * wv.z
              + fmaxf(qv.w + sv3, 0.f) * wv.w;
    }
  }

  // Combine d-halves: upper waves publish partials, lower waves accumulate.
  if (half) {
#pragma unroll
    for (int i = 0; i < QT; ++i) part[i][s] = acc[i];
  }
  __syncthreads();
  if (!half) {
#pragma unroll
    for (int i = 0; i < QT; ++i) acc[i] += part[i][s];
    // Per-block max (exact softmax invariant to the shared constant).
    float m = acc[0];
#pragma unroll
    for (int i = 1; i < QT; ++i) m = fmaxf(m, acc[i]);
#pragma unroll
    for (int off = 32; off > 0; off >>= 1)
      m = fmaxf(m, __shfl_xor(m, off));
    if ((t & 63) == 0) lds_wm[t >> 6] = m;
  }
  __syncthreads();
  if (!half) {
    float M = lds_wm[0];
#pragma unroll
    for (int w = 1; w < 5; ++w) M = fmaxf(M, lds_wm[w]);
#pragma unroll
    for (int i = 0; i < QT; ++i) {
      const float w = __expf(acc[i] - M);
      atomicAdd(&lds_cs[i * NWAY + lab], w);
    }
  }
  __syncthreads();
  if (t < QT * NWAY) {
    const int i = t / NWAY, c = t - i * NWAY;
    float tot = 0.f;
#pragma unroll
    for (int j = 0; j < NWAY; ++j) tot += lds_cs[i * NWAY + j];
    out[(size_t)(q0 + i) * NWAY + c] = lds_cs[i * NWAY + c] / tot;
  }
}

extern "C" void kernel_launch(void* const* d_in, const int* in_sizes, int n_in,
                              void* d_out, int out_size, void* d_ws, size_t ws_size,
                              hipStream_t stream) {
  const float* sup = (const float*)d_in[0];   // [320,256]
  const float* qe  = (const float*)d_in[1];   // [2048,256]
  const int*   lab = (const int*)d_in[2];     // [320] int32
  const float* W1  = (const float*)d_in[3];   // [512,256]
  const float* b1  = (const float*)d_in[4];   // [256]
  const float* W2  = (const float*)d_in[5];   // [256]
  // b2 (d_in[6]) softmax-invariant -> unused. n_way/n_shot hardcoded.
  float* out  = (float*)d_out;                // [2048,20]
  float* spbT = (float*)d_ws;                 // 256*320 floats, d-major
  float* qpr  = spbT + (size_t)DD * NS;       // 2048*256 floats

  proj_kernel<<<NQB + NSB, 256, 0, stream>>>(sup, qe, W1, b1, qpr, spbT);
  matchnet_kernel<<<NQ / QT, MT, 0, stream>>>(qpr, spbT, W2, lab, out);
}

// Round 3
// 101.651 us; speedup vs baseline: 1.4075x; 1.0157x over previous
//
#include <hip/hip_runtime.h>
#include <cstdint>

#define DD   256   // embedding dim
#define NS   320   // n_support
#define NQ   2048  // n_query
#define NWAY 20
#define QT   8     // queries per block (both kernels)
#define NQB  (NQ / QT)   // 256 query-proj blocks
#define NSB  (NS / QT)   // 40 support-proj blocks
#define CMAX 64    // max supports per class (labels are random, ~16 +/- 4)

// Fused projections, k-split across 512 threads (d = t&255, khalf = t>>8).
// W1 column loads coalesced b32; qe/sup row loads wave-uniform -> s_load.
// q blocks write qp row-major; s blocks write spbT d-major (+b1 folded).
__global__ __launch_bounds__(512) void proj_kernel(
    const float* __restrict__ sup, const float* __restrict__ qe,
    const float* __restrict__ W1, const float* __restrict__ b1,
    float* __restrict__ qp, float* __restrict__ spbT) {
  __shared__ float pacc[QT][DD];   // 8 KB k-combine buffer
  const int t  = threadIdx.x;
  const int d  = t & 255;
  const int kh = t >> 8;           // 0/1, wave-uniform
  const int b  = blockIdx.x;
  const bool isQ = (b < NQB);
  const int r0 = isQ ? b * QT : (b - NQB) * QT;
  const float* src   = isQ ? qe : sup;
  const float* wcol  = W1 + (isQ ? 0 : (size_t)DD * DD) + (size_t)(kh * 128) * DD + d;
  const float* rbase = src + __builtin_amdgcn_readfirstlane(r0 * DD + kh * 128);

  float acc[QT] = {0.f, 0.f, 0.f, 0.f, 0.f, 0.f, 0.f, 0.f};
#pragma unroll 8
  for (int k = 0; k < 128; ++k) {
    const float wv = wcol[(size_t)k * DD];       // coalesced, L2-resident
#pragma unroll
    for (int i = 0; i < QT; ++i)
      acc[i] += rbase[i * DD + k] * wv;          // uniform -> s_load (SMEM pipe)
  }
  if (kh) {
#pragma unroll
    for (int i = 0; i < QT; ++i) pacc[i][d] = acc[i];
  }
  __syncthreads();
  if (!kh) {
    if (isQ) {
#pragma unroll
      for (int i = 0; i < QT; ++i)
        qp[(size_t)(r0 + i) * DD + d] = acc[i] + pacc[i][d];   // coalesced
    } else {
      const float bb = b1[d];
#pragma unroll
      for (int i = 0; i < QT; ++i)
        spbT[d * NS + r0 + i] = acc[i] + pacc[i][d] + bb;      // tiny scatter (320 KB)
    }
  }
}

// matchnet: 256 blocks x 640 threads (10 waves). Waves 0-4: s=t, d in [0,128);
// waves 5-9: same supports, d in [128,256). Operand pipes: sv coalesced global
// b32 (VMEM, L2-resident), q/W2 wave-uniform -> s_load (SMEM). NO LDS in the
// main loop -> VALU-bound. Epilogue: combine halves, block softmax, per-class
// gather via label index lists (labels are NOT balanced per class).
__global__ __launch_bounds__(640) void matchnet_kernel(
    const float* __restrict__ qp, const float* __restrict__ spbT,
    const float* __restrict__ W2, const int* __restrict__ labels,
    float* __restrict__ out) {
  __shared__ float wexp[QT][NS];        // 10 KB: d-half partials, then exp weights
  __shared__ float wm[5];
  __shared__ float csum[QT * NWAY];
  __shared__ int   ccnt[NWAY];
  __shared__ short cidx[NWAY * CMAX];   // 2.5 KB
  const int t    = threadIdx.x;
  const int q0   = blockIdx.x * QT;
  const int half = t / NS;              // wave-uniform (NS = 5 waves)
  const int s    = t - half * NS;

  if (t < NWAY) ccnt[t] = 0;
  __syncthreads();
  if (!half) {                          // build per-class index lists once
    const int lab  = labels[s];
    const int slot = atomicAdd(&ccnt[lab], 1);
    cidx[lab * CMAX + slot] = (short)s;
  }

  const int d0 = half * (DD / 2);
  const float* qb = qp + __builtin_amdgcn_readfirstlane(q0 * DD + d0);
  const float* wb = W2 + d0;
  const float* sb = spbT + (size_t)d0 * NS + s;

  float acc[QT] = {0.f, 0.f, 0.f, 0.f, 0.f, 0.f, 0.f, 0.f};
#pragma unroll 2
  for (int dd = 0; dd < DD / 2; dd += 4) {
    const float sv0 = sb[(dd + 0) * NS];         // coalesced b32, L1/L2
    const float sv1 = sb[(dd + 1) * NS];
    const float sv2 = sb[(dd + 2) * NS];
    const float sv3 = sb[(dd + 3) * NS];
    const float4 wv = *(const float4*)(wb + dd); // uniform -> s_load_dwordx4
#pragma unroll
    for (int i = 0; i < QT; ++i) {
      const float4 qv = *(const float4*)(qb + i * DD + dd);  // uniform -> s_load
      acc[i] += fmaxf(qv.x + sv0, 0.f) * wv.x
              + fmaxf(qv.y + sv1, 0.f) * wv.y
              + fmaxf(qv.z + sv2, 0.f) * wv.z
              + fmaxf(qv.w + sv3, 0.f) * wv.w;
    }
  }

  // Combine d-halves.
  if (half) {
#pragma unroll
    for (int i = 0; i < QT; ++i) wexp[i][s] = acc[i];
  }
  __syncthreads();
  float m = -1e30f;
  if (!half) {
#pragma unroll
    for (int i = 0; i < QT; ++i) { acc[i] += wexp[i][s]; m = fmaxf(m, acc[i]); }
#pragma unroll
    for (int off = 32; off > 0; off >>= 1)
      m = fmaxf(m, __shfl_xor(m, off));
    if ((t & 63) == 0) wm[t >> 6] = m;
  }
  __syncthreads();
  if (!half) {
    const float M = fmaxf(fmaxf(fmaxf(wm[0], wm[1]), fmaxf(wm[2], wm[3])), wm[4]);
#pragma unroll
    for (int i = 0; i < QT; ++i) wexp[i][s] = __expf(acc[i] - M);
  }
  __syncthreads();
  // Per-(query,class) sums over that class's supports (variable count!).
  if (t < QT * NWAY) {
    const int i = t / NWAY, c = t - i * NWAY;
    const int n = ccnt[c];
    float sum = 0.f;
    for (int j = 0; j < n; ++j) sum += wexp[i][cidx[c * CMAX + j]];
    csum[t] = sum;
  }
  __syncthreads();
  if (t < QT * NWAY) {
    const int i = t / NWAY, c = t - i * NWAY;
    float tot = 0.f;
#pragma unroll
    for (int j = 0; j < NWAY; ++j) tot += csum[i * NWAY + j];
    out[(size_t)(q0 + i) * NWAY + c] = csum[t] / tot;
  }
}

extern "C" void kernel_launch(void* const* d_in, const int* in_sizes, int n_in,
                              void* d_out, int out_size, void* d_ws, size_t ws_size,
                              hipStream_t stream) {
  const float* sup = (const float*)d_in[0];   // [320,256]
  const float* qe  = (const float*)d_in[1];   // [2048,256]
  const int*   lab = (const int*)d_in[2];     // [320] int32
  const float* W1  = (const float*)d_in[3];   // [512,256]
  const float* b1  = (const float*)d_in[4];   // [256]
  const float* W2  = (const float*)d_in[5];   // [256]
  // b2 (d_in[6]) softmax-invariant -> unused. n_way/n_shot hardcoded.
  float* out  = (float*)d_out;                // [2048,20]
  float* spbT = (float*)d_ws;                 // 256*320 floats, d-major
  float* qpr  = spbT + (size_t)DD * NS;       // 2048*256 floats, row-major

  proj_kernel<<<NQB + NSB, 512, 0, stream>>>(sup, qe, W1, b1, qpr, spbT);
  matchnet_kernel<<<NQ / QT, 640, 0, stream>>>(qpr, spbT, W2, lab, out);
}

// Round 4
// 100.082 us; speedup vs baseline: 1.4295x; 1.0157x over previous
//
#include <hip/hip_runtime.h>
#include <cstdint>

#define DD   256   // embedding dim
#define NS   320   // n_support
#define NQ   2048  // n_query
#define NWAY 20
#define QTP  8     // queries/supports per proj block
#define QT   4     // queries per matchnet block
#define NQB  (NQ / QTP)  // 256 query-proj blocks
#define NSB  (NS / QTP)  // 40 support-proj blocks
#define CMAX 64    // max supports per class (labels random, ~16 each)

// Fused projections, k-split-4 across 1024 threads (d = t&255, kq = t>>8).
// W1 column loads coalesced b32; qe/sup row loads wave-uniform -> s_load.
// 296 blocks x 16 waves = 4.6 waves/SIMD (latency hiding).
__global__ __launch_bounds__(1024) void proj_kernel(
    const float* __restrict__ sup, const float* __restrict__ qe,
    const float* __restrict__ W1, const float* __restrict__ b1,
    float* __restrict__ qp, float* __restrict__ spbT) {
  __shared__ float pacc[3][QTP][DD];   // 24 KB k-combine buffer
  const int t  = threadIdx.x;
  const int d  = t & 255;
  const int kq = t >> 8;               // 0..3, wave-uniform
  const int b  = blockIdx.x;
  const bool isQ = (b < NQB);
  const int r0 = isQ ? b * QTP : (b - NQB) * QTP;
  const float* src   = isQ ? qe : sup;
  const float* wcol  = W1 + (isQ ? 0 : (size_t)DD * DD) + (size_t)(kq * 64) * DD + d;
  const float* rbase = src + __builtin_amdgcn_readfirstlane(r0 * DD + kq * 64);

  float acc[QTP] = {0.f, 0.f, 0.f, 0.f, 0.f, 0.f, 0.f, 0.f};
#pragma unroll 8
  for (int k = 0; k < 64; ++k) {
    const float wv = wcol[(size_t)k * DD];       // coalesced, L2-resident
#pragma unroll
    for (int i = 0; i < QTP; ++i)
      acc[i] += rbase[i * DD + k] * wv;          // uniform -> s_load (SMEM pipe)
  }
  if (kq) {
#pragma unroll
    for (int i = 0; i < QTP; ++i) pacc[kq - 1][i][d] = acc[i];
  }
  __syncthreads();
  if (kq == 0) {
    if (isQ) {
#pragma unroll
      for (int i = 0; i < QTP; ++i)
        qp[(size_t)(r0 + i) * DD + d] =
            acc[i] + pacc[0][i][d] + pacc[1][i][d] + pacc[2][i][d];  // coalesced
    } else {
      const float bb = b1[d];
#pragma unroll
      for (int i = 0; i < QTP; ++i)
        spbT[d * NS + r0 + i] =
            acc[i] + pacc[0][i][d] + pacc[1][i][d] + pacc[2][i][d] + bb;
    }
  }
}

// matchnet: 512 blocks x 640 threads (10 waves, 2 blocks/CU -> 5 waves/SIMD).
// Waves 0-4: s=t, d in [0,128); waves 5-9: same supports, d in [128,256).
// Operand pipes: sv coalesced global b32 (VMEM, L2), q/W2 wave-uniform ->
// s_load (SMEM). No LDS in main loop -> VALU-bound. Epilogue: combine halves,
// block softmax, per-class sums via label index lists (classes NOT balanced).
__global__ __launch_bounds__(640) void matchnet_kernel(
    const float* __restrict__ qp, const float* __restrict__ spbT,
    const float* __restrict__ W2, const int* __restrict__ labels,
    float* __restrict__ out) {
  __shared__ float wexp[QT][NS];        // d-half partials, then exp weights
  __shared__ float wm[5];
  __shared__ float csum[QT * NWAY];
  __shared__ int   ccnt[NWAY];
  __shared__ short cidx[NWAY * CMAX];
  const int t    = threadIdx.x;
  const int q0   = blockIdx.x * QT;
  const int half = t / NS;              // wave-uniform (NS = 5 waves)
  const int s    = t - half * NS;

  if (t < NWAY) ccnt[t] = 0;
  __syncthreads();
  if (!half) {                          // build per-class index lists
    const int lab  = labels[s];
    const int slot = atomicAdd(&ccnt[lab], 1);
    cidx[lab * CMAX + slot] = (short)s;
  }

  const int d0 = half * (DD / 2);
  const float* qb = qp + __builtin_amdgcn_readfirstlane(q0 * DD + d0);
  const float* wb = W2 + d0;
  const float* sb = spbT + (size_t)d0 * NS + s;

  float acc[QT] = {0.f, 0.f, 0.f, 0.f};
#pragma unroll 4
  for (int dd = 0; dd < DD / 2; dd += 4) {
    const float sv0 = sb[(dd + 0) * NS];         // coalesced b32, L1/L2
    const float sv1 = sb[(dd + 1) * NS];
    const float sv2 = sb[(dd + 2) * NS];
    const float sv3 = sb[(dd + 3) * NS];
    const float4 wv = *(const float4*)(wb + dd); // uniform -> s_load_dwordx4
#pragma unroll
    for (int i = 0; i < QT; ++i) {
      const float4 qv = *(const float4*)(qb + i * DD + dd);  // uniform -> s_load
      acc[i] += fmaxf(qv.x + sv0, 0.f) * wv.x
              + fmaxf(qv.y + sv1, 0.f) * wv.y
              + fmaxf(qv.z + sv2, 0.f) * wv.z
              + fmaxf(qv.w + sv3, 0.f) * wv.w;
    }
  }

  // Combine d-halves.
  if (half) {
#pragma unroll
    for (int i = 0; i < QT; ++i) wexp[i][s] = acc[i];
  }
  __syncthreads();
  float m = -1e30f;
  if (!half) {
#pragma unroll
    for (int i = 0; i < QT; ++i) { acc[i] += wexp[i][s]; m = fmaxf(m, acc[i]); }
#pragma unroll
    for (int off = 32; off > 0; off >>= 1)
      m = fmaxf(m, __shfl_xor(m, off));
    if ((t & 63) == 0) wm[t >> 6] = m;
  }
  __syncthreads();
  if (!half) {
    const float M = fmaxf(fmaxf(fmaxf(wm[0], wm[1]), fmaxf(wm[2], wm[3])), wm[4]);
#pragma unroll
    for (int i = 0; i < QT; ++i) wexp[i][s] = __expf(acc[i] - M);
  }
  __syncthreads();
  // Per-(query,class) sums over that class's supports (variable count).
  if (t < QT * NWAY) {
    const int i = t / NWAY, c = t - i * NWAY;
    const int n = ccnt[c];
    float sum = 0.f;
    for (int j = 0; j < n; ++j) sum += wexp[i][cidx[c * CMAX + j]];
    csum[t] = sum;
  }
  __syncthreads();
  if (t < QT * NWAY) {
    const int i = t / NWAY, c = t - i * NWAY;
    float tot = 0.f;
#pragma unroll
    for (int j = 0; j < NWAY; ++j) tot += csum[i * NWAY + j];
    out[(size_t)(q0 + i) * NWAY + c] = csum[t] / tot;
  }
}

extern "C" void kernel_launch(void* const* d_in, const int* in_sizes, int n_in,
                              void* d_out, int out_size, void* d_ws, size_t ws_size,
                              hipStream_t stream) {
  const float* sup = (const float*)d_in[0];   // [320,256]
  const float* qe  = (const float*)d_in[1];   // [2048,256]
  const int*   lab = (const int*)d_in[2];     // [320] int32
  const float* W1  = (const float*)d_in[3];   // [512,256]
  const float* b1  = (const float*)d_in[4];   // [256]
  const float* W2  = (const float*)d_in[5];   // [256]
  // b2 (d_in[6]) softmax-invariant -> unused. n_way/n_shot hardcoded.
  float* out  = (float*)d_out;                // [2048,20]
  float* spbT = (float*)d_ws;                 // 256*320 floats, d-major
  float* qpr  = spbT + (size_t)DD * NS;       // 2048*256 floats, row-major

  proj_kernel<<<NQB + NSB, 1024, 0, stream>>>(sup, qe, W1, b1, qpr, spbT);
  matchnet_kernel<<<NQ / QT, 640, 0, stream>>>(qpr, spbT, W2, lab, out);
}